// Round 4
// baseline (362.918 us; speedup 1.0000x reference)
//
#include <hip/hip_runtime.h>

typedef _Float16 half8 __attribute__((ext_vector_type(8)));
typedef _Float16 half4 __attribute__((ext_vector_type(4)));
typedef float    f32x4 __attribute__((ext_vector_type(4)));

#define T_TOK 16384
#define D_DIM 4096
#define E_EXP 128
#define CAP   256
#define BM    64
#define BK    64
#define NT    (D_DIM / BK)   // 64 K-steps
#define A_ROW 272            // padded LDS row stride (8 groups*32B + 16 pad)
#define A_BUF (BM * A_ROW)   // 17408 B per buffer
#define SMEM  (2 * A_BUF)    // 34816 B; logits alias needs 64*129*4 = 33024

// ---------------------------------------------------------------------------
// Kernel 0: wg (fp32) -> scaled split-fp16 planes. w64 = wg*64 (exact pow2
// rescale keeps w_m in fp16 normal range); h = fp16(w64), m = fp16(w64 - h).
// ---------------------------------------------------------------------------
__global__ __launch_bounds__(256) void prep_wg(
    const float* __restrict__ wg, _Float16* __restrict__ wh,
    _Float16* __restrict__ wm)
{
    const int i = (blockIdx.x * 256 + threadIdx.x) * 4;
    const f32x4 v = *reinterpret_cast<const f32x4*>(wg + i);
    half4 h, m;
#pragma unroll
    for (int j = 0; j < 4; j++) {
        const float s = v[j] * 64.0f;
        const _Float16 hh = (_Float16)s;
        h[j] = hh;
        m[j] = (_Float16)(s - (float)hh);
    }
    *reinterpret_cast<half4*>(wh + i) = h;
    *reinterpret_cast<half4*>(wm + i) = m;
}

// ---------------------------------------------------------------------------
// Kernel A: hybrid MFMA GEMM. A (x rows): coalesced HBM load -> in-reg fp16
// h/m split -> double-buffered LDS; B (wg planes): fragments direct from
// global (L2/L3-resident; 4 waves per column-group share loads via L1).
// 512 thr = 8 waves = 4 row-groups(16 rows) x 2 col-groups(64 cols).
// 3-product split MFMA (AhBh + AhBm + AmBh). One __syncthreads per K-step.
// ---------------------------------------------------------------------------
__global__ __launch_bounds__(512, 2) void gemm_gate(
    const float* __restrict__ x, const _Float16* __restrict__ wh,
    const _Float16* __restrict__ wm, float* __restrict__ out,
    float* __restrict__ me)
{
    __shared__ char smem[SMEM];

    const int tid  = threadIdx.x;
    const int row0 = blockIdx.x * BM;
    const int lane = tid & 63;
    const int wid  = tid >> 6;
    const int rg   = wid >> 1;   // row-group 0..3 (16 rows each)
    const int cg   = wid & 1;    // col-group 0..1 (64 cols each)
    const int lr   = lane & 15;
    const int lq   = lane >> 4;  // k-span within fragment (8 halfs)

    // A staging role: thread t loads x[row0 + (t>>3)][g*8..g*8+8), g = t&7
    const int srow = tid >> 3;
    const int sg   = tid & 7;
    const float* xA = x + (size_t)(row0 + srow) * D_DIM + sg * 8;
    char* const swr = smem + srow * A_ROW + sg * 32;

    // B fragment bases (per lane): expert row (cg*64 + cf*16 + lr), k lq*8
    const size_t bbase = (size_t)(cg * 64 + lr) * D_DIM + lq * 8;
    const _Float16* whB = wh + bbase;
    const _Float16* wmB = wm + bbase;

    // A fragment read base: row rg*16+lr, group ks*4+lq
    const char* const ard = smem + (rg * 16 + lr) * A_ROW + lq * 32;

    f32x4 acc[4];
#pragma unroll
    for (int cf = 0; cf < 4; cf++) acc[cf] = (f32x4)0.0f;

    // ---- prologue: stage tile 0 into buffer 0 ----
    {
        const f32x4 v0 = *reinterpret_cast<const f32x4*>(xA);
        const f32x4 v1 = *reinterpret_cast<const f32x4*>(xA + 4);
        half8 h, m;
#pragma unroll
        for (int j = 0; j < 4; j++) {
            _Float16 hh = (_Float16)v0[j];
            h[j] = hh; m[j] = (_Float16)(v0[j] - (float)hh);
            hh = (_Float16)v1[j];
            h[4 + j] = hh; m[4 + j] = (_Float16)(v1[j] - (float)hh);
        }
        *reinterpret_cast<half8*>(swr)      = h;
        *reinterpret_cast<half8*>(swr + 16) = m;
    }
    __syncthreads();

    // ---- main K loop ----
    for (int t = 0; t < NT; ++t) {
        const int cur = t & 1;

        // 1. A prefetch for tile t+1 (wraps harmlessly at the end)
        const int tk = ((t + 1) & (NT - 1)) * BK;
        const f32x4 n0 = *reinterpret_cast<const f32x4*>(xA + tk);
        const f32x4 n1 = *reinterpret_cast<const f32x4*>(xA + tk + 4);

        // 2. B fragments for this step, direct from global
        half8 bh[2][4], bl[2][4];
        const int kb = t * BK;
#pragma unroll
        for (int ks = 0; ks < 2; ks++)
#pragma unroll
            for (int cf = 0; cf < 4; cf++) {
                const size_t o = (size_t)cf * 16 * D_DIM + kb + ks * 32;
                bh[ks][cf] = *reinterpret_cast<const half8*>(whB + o);
                bl[ks][cf] = *reinterpret_cast<const half8*>(wmB + o);
            }

        // 3. A fragments from LDS + MFMA
#pragma unroll
        for (int ks = 0; ks < 2; ks++) {
            const char* ab = ard + cur * A_BUF + ks * 128;
            const half8 Ah = *reinterpret_cast<const half8*>(ab);
            const half8 Am = *reinterpret_cast<const half8*>(ab + 16);
#pragma unroll
            for (int cf = 0; cf < 4; cf++) {
                acc[cf] = __builtin_amdgcn_mfma_f32_16x16x32_f16(Am, bh[ks][cf], acc[cf], 0, 0, 0);
                acc[cf] = __builtin_amdgcn_mfma_f32_16x16x32_f16(Ah, bl[ks][cf], acc[cf], 0, 0, 0);
                acc[cf] = __builtin_amdgcn_mfma_f32_16x16x32_f16(Ah, bh[ks][cf], acc[cf], 0, 0, 0);
            }
        }

        // 4. convert + stage tile t+1 into the other buffer
        {
            half8 h, m;
#pragma unroll
            for (int j = 0; j < 4; j++) {
                _Float16 hh = (_Float16)n0[j];
                h[j] = hh; m[j] = (_Float16)(n0[j] - (float)hh);
                hh = (_Float16)n1[j];
                h[4 + j] = hh; m[4 + j] = (_Float16)(n1[j] - (float)hh);
            }
            char* wr = swr + (cur ^ 1) * A_BUF;
            *reinterpret_cast<half8*>(wr)      = h;
            *reinterpret_cast<half8*>(wr + 16) = m;
        }
        __syncthreads();
    }

    // ---- epilogue: logits -> LDS (alias A buffers), scale by 1/64 ----
    float* lg = reinterpret_cast<float*>(smem);  // [64][129]
#pragma unroll
    for (int cf = 0; cf < 4; cf++)
#pragma unroll
        for (int r = 0; r < 4; r++) {
            const int row = rg * 16 + lq * 4 + r;
            const int col = cg * 64 + cf * 16 + lr;
            lg[row * 129 + col] = acc[cf][r] * 0.015625f;
        }
    __syncthreads();

    if (tid < BM) {
        const int r = tid;
        const int t = row0 + r;
        float m1 = -1e30f, m2 = -1e30f;
        int   i1 = 0, i2 = 0;
        for (int e = 0; e < E_EXP; e++) {
            const float v = lg[r * 129 + e];
            if (v > m1)      { m2 = m1; i2 = i1; m1 = v; i1 = e; }
            else if (v > m2) { m2 = v; i2 = e; }
        }
        float s = 0.0f;
        for (int e = 0; e < E_EXP; e++) s += __expf(lg[r * 129 + e] - m1);
        const float inv = 1.0f / s;

        out[3 + 0 * T_TOK + t] = (float)i1;
        out[3 + 1 * T_TOK + t] = (float)i2;
        out[3 + 4 * T_TOK + t] = inv;
        out[3 + 5 * T_TOK + t] = __expf(m2 - m1) * inv;

        for (int e = 0; e < E_EXP; e++)
            lg[r * 129 + e] = __expf(lg[r * 129 + e] - m1) * inv;
    }
    __syncthreads();

    if (tid < E_EXP) {
        float s = 0.0f;
        for (int r = 0; r < BM; r++) s += lg[r * 129 + tid];
        atomicAdd(&me[tid], s);
    }
}

// ---------------------------------------------------------------------------
// Kernel B: per-expert rank (cumsum) for locations1_s / locations2_s + ce.
// ---------------------------------------------------------------------------
__global__ __launch_bounds__(256) void rank_kernel(
    float* __restrict__ out, float* __restrict__ ce)
{
    const int e    = blockIdx.x;
    const int tid  = threadIdx.x;
    const int lane = tid & 63;
    const int w    = tid >> 6;

    __shared__ int wtot[4];

    const float* idx1 = out + 3;
    const float* idx2 = out + 3 + T_TOK;
    float* loc1 = out + 3 + 2 * T_TOK;
    float* loc2 = out + 3 + 3 * T_TOK;

    const unsigned long long below = (1ull << lane) - 1ull;
    int base = 0;

    for (int t0 = 0; t0 < T_TOK; t0 += 256) {
        const int t = t0 + tid;
        const int f = ((int)idx1[t] == e);
        const unsigned long long m = __ballot(f);
        const int pre = __popcll(m & below);
        const int tot = __popcll(m);
        if (lane == 0) wtot[w] = tot;
        __syncthreads();
        int off = 0;
        for (int i = 0; i < w; i++) off += wtot[i];
        const int all = wtot[0] + wtot[1] + wtot[2] + wtot[3];
        if (f) {
            const int rank = base + off + pre;
            loc1[t] = (rank < CAP) ? (float)rank : 0.0f;
        }
        base += all;
        __syncthreads();
    }

    const int count1 = base;
    if (tid == 0) ce[e] = (float)((count1 < CAP) ? count1 : CAP);

    for (int t0 = 0; t0 < T_TOK; t0 += 256) {
        const int t = t0 + tid;
        const int f = ((int)idx2[t] == e);
        const unsigned long long m = __ballot(f);
        const int pre = __popcll(m & below);
        const int tot = __popcll(m);
        if (lane == 0) wtot[w] = tot;
        __syncthreads();
        int off = 0;
        for (int i = 0; i < w; i++) off += wtot[i];
        const int all = wtot[0] + wtot[1] + wtot[2] + wtot[3];
        if (f) {
            const int rank = base + off + pre;
            loc2[t] = (rank < CAP) ? (float)rank : 0.0f;
        }
        base += all;
        __syncthreads();
    }
}

// ---------------------------------------------------------------------------
// Kernel C: l_aux = sum(me*ce) * E/(T*T); plus capacity and E constants.
// ---------------------------------------------------------------------------
__global__ __launch_bounds__(128) void finalize_kernel(
    const float* __restrict__ me, const float* __restrict__ ce,
    float* __restrict__ out)
{
    __shared__ float red[2];
    const int tid = threadIdx.x;
    float p = me[tid] * ce[tid];
#pragma unroll
    for (int o = 32; o > 0; o >>= 1) p += __shfl_down(p, o);
    if ((tid & 63) == 0) red[tid >> 6] = p;
    __syncthreads();
    if (tid == 0) {
        const float tot = red[0] + red[1];
        out[0] = tot * ((float)E_EXP / ((float)T_TOK * (float)T_TOK));
        out[1] = (float)CAP;
        out[2] = (float)E_EXP;
    }
}

extern "C" void kernel_launch(void* const* d_in, const int* in_sizes, int n_in,
                              void* d_out, int out_size, void* d_ws, size_t ws_size,
                              hipStream_t stream)
{
    const float* x  = (const float*)d_in[0];
    const float* wg = (const float*)d_in[1];
    float* out = (float*)d_out;

    float* me = (float*)d_ws;            // 128 floats
    float* ce = me + 128;                // 128 floats
    _Float16* wh = (_Float16*)((char*)d_ws + 1024);            // 1 MB
    _Float16* wm = wh + (size_t)E_EXP * D_DIM;                 // 1 MB

    hipMemsetAsync(me, 0, 128 * sizeof(float), stream);
    prep_wg<<<(E_EXP * D_DIM) / (256 * 4), 256, 0, stream>>>(wg, wh, wm);
    gemm_gate<<<T_TOK / BM, 512, 0, stream>>>(x, wh, wm, out, me);
    rank_kernel<<<E_EXP, 256, 0, stream>>>(out, ce);
    finalize_kernel<<<1, 128, 0, stream>>>(me, ce, out);
}

// Round 5
// 211.487 us; speedup vs baseline: 1.7160x; 1.7160x over previous
//
#include <hip/hip_runtime.h>

typedef _Float16 half8 __attribute__((ext_vector_type(8)));
typedef _Float16 half4 __attribute__((ext_vector_type(4)));
typedef float    f32x4 __attribute__((ext_vector_type(4)));

#define T_TOK 16384
#define D_DIM 4096
#define E_EXP 128
#define CAP   256
#define BM    32
#define BK    32
#define NT    (D_DIM / BK)   // 128 K-steps

// LDS map (bytes):
//  [A buf0 4096][A buf1 4096][B buf0 16384][B buf1 16384] = 40960
//  A buf: 32 rows x 128 B  (8 chunks of 16B: h c0..3 | m c4..7, chunk ^= row&7)
//  B buf: h-plane 8192 | m-plane 8192; per expert 64 B (chunk ^= (e>>1)&3)
#define A_BUF 4096
#define B_OFF 8192
#define B_BUF 16384
#define SMEM  (B_OFF + 2 * B_BUF)   // 40960; logits alias needs 32*129*4=16512

__device__ __forceinline__ void gld_lds16(const void* g, void* l) {
    __builtin_amdgcn_global_load_lds(
        (const __attribute__((address_space(1))) unsigned int*)g,
        (__attribute__((address_space(3))) unsigned int*)l, 16, 0, 0);
}

// ---------------------------------------------------------------------------
// Kernel 0: wg (fp32) -> K-step-tiled, pre-swizzled split-fp16 planes.
// wt halfs layout: [step s][h: e*32 + (c^((e>>1)&3))*8][m at +4096]
// Scaled by 64 (exact pow2) so the m-plane stays in fp16 normal range.
// ---------------------------------------------------------------------------
__global__ __launch_bounds__(256) void prep_wt(
    const float* __restrict__ wg, _Float16* __restrict__ wt)
{
    const int t = blockIdx.x * 256 + threadIdx.x;  // 65536 threads
    const int c = t & 3;
    const int e = (t >> 2) & 127;
    const int s = t >> 9;

    const float* src = wg + (size_t)e * D_DIM + s * 32 + c * 8;
    const f32x4 v0 = *reinterpret_cast<const f32x4*>(src);
    const f32x4 v1 = *reinterpret_cast<const f32x4*>(src + 4);

    half8 h, m;
#pragma unroll
    for (int j = 0; j < 4; j++) {
        float sv = v0[j] * 64.0f;
        _Float16 hh = (_Float16)sv;
        h[j] = hh; m[j] = (_Float16)(sv - (float)hh);
        sv = v1[j] * 64.0f;
        hh = (_Float16)sv;
        h[4 + j] = hh; m[4 + j] = (_Float16)(sv - (float)hh);
    }
    const int csw = c ^ ((e >> 1) & 3);
    _Float16* dst = wt + (size_t)s * 8192 + e * 32 + csw * 8;
    *reinterpret_cast<half8*>(dst)        = h;
    *reinterpret_cast<half8*>(dst + 4096) = m;
}

// ---------------------------------------------------------------------------
// Kernel A: MFMA GEMM, BM=32, grid 512 (2 blocks/CU for TLP overlap).
// A: x rows -> in-reg fp16 h/m split -> double-buffered LDS (XOR-swizzled).
// B: K-tiled pre-swizzled planes -> LDS via global_load_lds width=16.
// 4 waves; wave w owns experts [w*32, w*32+32). 3-product split MFMA.
// ---------------------------------------------------------------------------
__global__ __launch_bounds__(256, 2) void gemm_gate(
    const float* __restrict__ x, const _Float16* __restrict__ wt,
    float* __restrict__ out, float* __restrict__ me)
{
    __shared__ char smem[SMEM];

    const int tid  = threadIdx.x;
    const int row0 = blockIdx.x * BM;
    const int lane = tid & 63;
    const int w    = tid >> 6;   // wave 0..3
    const int lr   = lane & 15;
    const int lq   = lane >> 4;

    // A staging role: thread t loads x[row0 + (t>>3)][k + (t&7)*4 .. +4)
    const int srow = tid >> 3;
    const int sg   = tid & 7;
    const float* xA = x + (size_t)(row0 + srow) * D_DIM + sg * 4;
    const int awr_h = srow * 128 + (((sg >> 1)    ) ^ (srow & 7)) * 16 + (sg & 1) * 8;
    const int awr_m = srow * 128 + (((sg >> 1) + 4) ^ (srow & 7)) * 16 + (sg & 1) * 8;

    // B glds role: wave w copies chunks w*4..w*4+3 (1 KB each)
    const _Float16* bsrc = wt + w * 2048 + lane * 8;
    const int bdst = B_OFF + w * 4096;

    // fragment read offsets
    const int a_sw = lr & 7;
    const int b_sw = (lq ^ ((lr >> 1) & 3)) * 16;

    f32x4 acc[2][2];
#pragma unroll
    for (int i = 0; i < 2; i++)
#pragma unroll
        for (int j = 0; j < 2; j++) acc[i][j] = (f32x4)0.0f;

    // ---- prologue: stage step 0 into buf 0 ----
    {
        const f32x4 av = *reinterpret_cast<const f32x4*>(xA);
        half4 ah, am;
#pragma unroll
        for (int j = 0; j < 4; j++) {
            const _Float16 hh = (_Float16)av[j];
            ah[j] = hh; am[j] = (_Float16)(av[j] - (float)hh);
        }
        *reinterpret_cast<half4*>(smem + awr_h) = ah;
        *reinterpret_cast<half4*>(smem + awr_m) = am;
#pragma unroll
        for (int i = 0; i < 4; i++)
            gld_lds16(bsrc + i * 512, smem + bdst + i * 1024);
    }
    __syncthreads();

    // ---- main K loop: 1 barrier/step; 2 blocks/CU overlap the drains ----
    for (int t = 0; t < NT; ++t) {
        const int cur = t & 1;
        const int nxt = cur ^ 1;
        const int t1  = (t + 1) & (NT - 1);   // wraps harmlessly at the end

        // prefetch A regs + issue B glds for step t+1 into buf nxt
        const f32x4 av = *reinterpret_cast<const f32x4*>(xA + t1 * BK);
        const _Float16* bs = bsrc + (size_t)t1 * 8192;
#pragma unroll
        for (int i = 0; i < 4; i++)
            gld_lds16(bs + i * 512, smem + bdst + nxt * B_BUF + i * 1024);

        // fragments from buf cur
        const char* ab = smem + cur * A_BUF;
        const char* bb = smem + B_OFF + cur * B_BUF;
        half8 Ah[2], Am[2], Bh[2], Bm[2];
#pragma unroll
        for (int rf = 0; rf < 2; rf++) {
            const int rbase = (rf * 16 + lr) * 128;
            Ah[rf] = *reinterpret_cast<const half8*>(ab + rbase + ((lq    ) ^ a_sw) * 16);
            Am[rf] = *reinterpret_cast<const half8*>(ab + rbase + ((lq + 4) ^ a_sw) * 16);
        }
#pragma unroll
        for (int cf = 0; cf < 2; cf++) {
            const int e = w * 32 + cf * 16 + lr;
            Bh[cf] = *reinterpret_cast<const half8*>(bb + e * 64 + b_sw);
            Bm[cf] = *reinterpret_cast<const half8*>(bb + 8192 + e * 64 + b_sw);
        }

#pragma unroll
        for (int rf = 0; rf < 2; rf++)
#pragma unroll
            for (int cf = 0; cf < 2; cf++) {
                acc[rf][cf] = __builtin_amdgcn_mfma_f32_16x16x32_f16(Am[rf], Bh[cf], acc[rf][cf], 0, 0, 0);
                acc[rf][cf] = __builtin_amdgcn_mfma_f32_16x16x32_f16(Ah[rf], Bm[cf], acc[rf][cf], 0, 0, 0);
                acc[rf][cf] = __builtin_amdgcn_mfma_f32_16x16x32_f16(Ah[rf], Bh[cf], acc[rf][cf], 0, 0, 0);
            }

        // convert + stage A(t+1) into buf nxt
        {
            half4 ah, am;
#pragma unroll
            for (int j = 0; j < 4; j++) {
                const _Float16 hh = (_Float16)av[j];
                ah[j] = hh; am[j] = (_Float16)(av[j] - (float)hh);
            }
            *reinterpret_cast<half4*>(smem + nxt * A_BUF + awr_h) = ah;
            *reinterpret_cast<half4*>(smem + nxt * A_BUF + awr_m) = am;
        }
        __syncthreads();
    }

    // ---- epilogue: logits -> LDS (alias buffers), scale by 1/64 ----
    float* lg = reinterpret_cast<float*>(smem);  // [32][129]
#pragma unroll
    for (int rf = 0; rf < 2; rf++)
#pragma unroll
        for (int cf = 0; cf < 2; cf++)
#pragma unroll
            for (int r = 0; r < 4; r++) {
                const int row = rf * 16 + lq * 4 + r;
                const int col = w * 32 + cf * 16 + lr;
                lg[row * 129 + col] = acc[rf][cf][r] * 0.015625f;
            }
    __syncthreads();

    if (tid < BM) {
        const int r = tid;
        const int t = row0 + r;
        float m1 = -1e30f, m2 = -1e30f;
        int   i1 = 0, i2 = 0;
        for (int e = 0; e < E_EXP; e++) {
            const float v = lg[r * 129 + e];
            if (v > m1)      { m2 = m1; i2 = i1; m1 = v; i1 = e; }
            else if (v > m2) { m2 = v; i2 = e; }
        }
        float s = 0.0f;
        for (int e = 0; e < E_EXP; e++) s += __expf(lg[r * 129 + e] - m1);
        const float inv = 1.0f / s;

        out[3 + 0 * T_TOK + t] = (float)i1;
        out[3 + 1 * T_TOK + t] = (float)i2;
        out[3 + 4 * T_TOK + t] = inv;
        out[3 + 5 * T_TOK + t] = __expf(m2 - m1) * inv;

        for (int e = 0; e < E_EXP; e++)
            lg[r * 129 + e] = __expf(lg[r * 129 + e] - m1) * inv;
    }
    __syncthreads();

    if (tid < E_EXP) {
        float s = 0.0f;
        for (int r = 0; r < BM; r++) s += lg[r * 129 + tid];
        atomicAdd(&me[tid], s);
    }
}

// ---------------------------------------------------------------------------
// Kernel B: per-expert rank (cumsum) for locations1_s / locations2_s + ce.
// ---------------------------------------------------------------------------
__global__ __launch_bounds__(256) void rank_kernel(
    float* __restrict__ out, float* __restrict__ ce)
{
    const int e    = blockIdx.x;
    const int tid  = threadIdx.x;
    const int lane = tid & 63;
    const int w    = tid >> 6;

    __shared__ int wtot[4];

    const float* idx1 = out + 3;
    const float* idx2 = out + 3 + T_TOK;
    float* loc1 = out + 3 + 2 * T_TOK;
    float* loc2 = out + 3 + 3 * T_TOK;

    const unsigned long long below = (1ull << lane) - 1ull;
    int base = 0;

    for (int t0 = 0; t0 < T_TOK; t0 += 256) {
        const int t = t0 + tid;
        const int f = ((int)idx1[t] == e);
        const unsigned long long m = __ballot(f);
        const int pre = __popcll(m & below);
        const int tot = __popcll(m);
        if (lane == 0) wtot[w] = tot;
        __syncthreads();
        int off = 0;
        for (int i = 0; i < w; i++) off += wtot[i];
        const int all = wtot[0] + wtot[1] + wtot[2] + wtot[3];
        if (f) {
            const int rank = base + off + pre;
            loc1[t] = (rank < CAP) ? (float)rank : 0.0f;
        }
        base += all;
        __syncthreads();
    }

    const int count1 = base;
    if (tid == 0) ce[e] = (float)((count1 < CAP) ? count1 : CAP);

    for (int t0 = 0; t0 < T_TOK; t0 += 256) {
        const int t = t0 + tid;
        const int f = ((int)idx2[t] == e);
        const unsigned long long m = __ballot(f);
        const int pre = __popcll(m & below);
        const int tot = __popcll(m);
        if (lane == 0) wtot[w] = tot;
        __syncthreads();
        int off = 0;
        for (int i = 0; i < w; i++) off += wtot[i];
        const int all = wtot[0] + wtot[1] + wtot[2] + wtot[3];
        if (f) {
            const int rank = base + off + pre;
            loc2[t] = (rank < CAP) ? (float)rank : 0.0f;
        }
        base += all;
        __syncthreads();
    }
}

// ---------------------------------------------------------------------------
// Kernel C: l_aux = sum(me*ce) * E/(T*T); plus capacity and E constants.
// ---------------------------------------------------------------------------
__global__ __launch_bounds__(128) void finalize_kernel(
    const float* __restrict__ me, const float* __restrict__ ce,
    float* __restrict__ out)
{
    __shared__ float red[2];
    const int tid = threadIdx.x;
    float p = me[tid] * ce[tid];
#pragma unroll
    for (int o = 32; o > 0; o >>= 1) p += __shfl_down(p, o);
    if ((tid & 63) == 0) red[tid >> 6] = p;
    __syncthreads();
    if (tid == 0) {
        const float tot = red[0] + red[1];
        out[0] = tot * ((float)E_EXP / ((float)T_TOK * (float)T_TOK));
        out[1] = (float)CAP;
        out[2] = (float)E_EXP;
    }
}

extern "C" void kernel_launch(void* const* d_in, const int* in_sizes, int n_in,
                              void* d_out, int out_size, void* d_ws, size_t ws_size,
                              hipStream_t stream)
{
    const float* x  = (const float*)d_in[0];
    const float* wg = (const float*)d_in[1];
    float* out = (float*)d_out;

    float* me = (float*)d_ws;                        // 128 floats
    float* ce = me + 128;                            // 128 floats
    _Float16* wt = (_Float16*)((char*)d_ws + 1024);  // 2 MB tiled planes

    hipMemsetAsync(me, 0, 128 * sizeof(float), stream);
    prep_wt<<<256, 256, 0, stream>>>(wg, wt);
    gemm_gate<<<T_TOK / BM, 256, 0, stream>>>(x, wt, out, me);
    rank_kernel<<<E_EXP, 256, 0, stream>>>(out, ce);
    finalize_kernel<<<1, 128, 0, stream>>>(me, ce, out);
}

// Round 6
// 143.791 us; speedup vs baseline: 2.5239x; 1.4708x over previous
//
#include <hip/hip_runtime.h>

typedef _Float16 half8 __attribute__((ext_vector_type(8)));
typedef _Float16 half4 __attribute__((ext_vector_type(4)));
typedef float    f32x4 __attribute__((ext_vector_type(4)));

#define T_TOK 16384
#define D_DIM 4096
#define E_EXP 128
#define CAP   256
#define BM    32
#define BK    32
#define NT    64          // K-steps per pipe (half of 128)

// A LDS: [pipe][buf][row 0..31][128 B: h halfs 0..31 | m halfs 0..31]
#define A_BUF  4096
#define A_PIPE (2 * A_BUF)

// ---------------------------------------------------------------------------
// Kernel 0: wg (fp32) -> K-step-tiled split-fp16 planes, scaled by 64.
// Step s block (16384 B): h plane 8192 B | m plane 8192 B; expert e at e*64 B.
// ---------------------------------------------------------------------------
__global__ __launch_bounds__(256) void prep_wt(
    const float* __restrict__ wg, _Float16* __restrict__ wt)
{
    const int t = blockIdx.x * 256 + threadIdx.x;  // 65536 threads
    const int c = t & 3;
    const int e = (t >> 2) & 127;
    const int s = t >> 9;

    const float* src = wg + (size_t)e * D_DIM + s * 32 + c * 8;
    const f32x4 v0 = *reinterpret_cast<const f32x4*>(src);
    const f32x4 v1 = *reinterpret_cast<const f32x4*>(src + 4);

    half8 h, m;
#pragma unroll
    for (int j = 0; j < 4; j++) {
        float sv = v0[j] * 64.0f;
        _Float16 hh = (_Float16)sv;
        h[j] = hh; m[j] = (_Float16)(sv - (float)hh);
        sv = v1[j] * 64.0f;
        hh = (_Float16)sv;
        h[4 + j] = hh; m[4 + j] = (_Float16)(sv - (float)hh);
    }
    _Float16* dst = wt + (size_t)s * 8192 + e * 32 + c * 8;
    *reinterpret_cast<half8*>(dst)        = h;
    *reinterpret_cast<half8*>(dst + 4096) = m;
}

// ---------------------------------------------------------------------------
// Kernel A: dual-K-pipe MFMA GEMM + fused gate epilogue.
// 512 thr = 8 waves; waves 0-3 = K-half 0, waves 4-7 = K-half 1.
// A: x -> regs (2-deep) -> fp16 h/m split -> LDS dbuf (per pipe, no swizzle:
//    reads/writes are <=2-way bank-aliased = free).
// B: K-tiled wt planes direct to registers (1-deep dbuf), contiguous 1KB
//    wave-bursts from L2-hot 2MB.  No vmem drain at the barrier: the only
//    cross-wave hazard is the A ds_write -> s_waitcnt lgkmcnt(0) + s_barrier.
// ---------------------------------------------------------------------------
__global__ __launch_bounds__(512, 4) void gemm_gate(
    const float* __restrict__ x, const _Float16* __restrict__ wt,
    float* __restrict__ out, float* __restrict__ me)
{
    __shared__ char smem[2 * A_PIPE];      // 16 KB A tiles
    __shared__ float lg[BM][E_EXP + 1];    // 16.5 KB logits

    const int tid  = threadIdx.x;
    const int row0 = blockIdx.x * BM;
    const int lane = tid & 63;
    const int w    = tid >> 6;
    const int kp   = w >> 2;     // K-pipe 0/1
    const int wl   = w & 3;      // expert group: experts wl*32 .. +32
    const int lr   = lane & 15;
    const int lq   = lane >> 4;

    // ---- A staging role: threads 0-255 stage pipe 0, 256-511 pipe 1 ----
    const int sp   = tid >> 8;
    const int srow = (tid >> 3) & 31;
    const int sg   = tid & 7;
    const float* xA = x + (size_t)(row0 + srow) * D_DIM + sp * 2048 + sg * 4;
    char* const awr = smem + sp * A_PIPE + srow * 128 + sg * 8;  // h; m at +64

    // ---- A fragment read base (pipe kp) ----
    const char* const ard = smem + kp * A_PIPE + lr * 128 + lq * 16;  // +rf*2048

    // ---- B fragment base: step s = kp*64 + t; 16 B per lane ----
    const _Float16* const wtB =
        wt + (size_t)(kp * 64) * 8192 + (wl * 32 + lr) * 32 + lq * 8;
    // offsets: + t*8192 + cf*512 + plane*4096

    f32x4 acc[2][2];
#pragma unroll
    for (int i = 0; i < 2; i++)
#pragma unroll
        for (int j = 0; j < 2; j++) acc[i][j] = (f32x4)0.0f;

#define CONV_WRITE(av, buf)                                                   \
    {                                                                         \
        half4 ah, am;                                                         \
        _Pragma("unroll") for (int j = 0; j < 4; j++) {                       \
            const _Float16 hh = (_Float16)av[j];                              \
            ah[j] = hh; am[j] = (_Float16)(av[j] - (float)hh);                \
        }                                                                     \
        *reinterpret_cast<half4*>(awr + (buf) * A_BUF)      = ah;             \
        *reinterpret_cast<half4*>(awr + (buf) * A_BUF + 64) = am;             \
    }

#define LOAD_B(Bh, Bm, t)                                                     \
    {                                                                         \
        const _Float16* bp = wtB + (size_t)((t) & 63) * 8192;                 \
        Bh[0] = *reinterpret_cast<const half8*>(bp);                          \
        Bh[1] = *reinterpret_cast<const half8*>(bp + 512);                    \
        Bm[0] = *reinterpret_cast<const half8*>(bp + 4096);                   \
        Bm[1] = *reinterpret_cast<const half8*>(bp + 4096 + 512);             \
    }

#define BAR()                                                                 \
    asm volatile("s_waitcnt lgkmcnt(0)" ::: "memory");                        \
    __builtin_amdgcn_sched_barrier(0);                                        \
    __builtin_amdgcn_s_barrier();                                             \
    __builtin_amdgcn_sched_barrier(0);

#define STEP(cur, AVC, AVN, BHC, BMC, BHN, BMN, t)                            \
    {                                                                         \
        AVN = *reinterpret_cast<const f32x4*>(xA + (((t) + 2) & 63) * BK);    \
        LOAD_B(BHN, BMN, (t) + 1);                                            \
        half8 Ah[2], Am[2];                                                   \
        _Pragma("unroll") for (int rf = 0; rf < 2; rf++) {                    \
            const char* ab = ard + (cur) * A_BUF + rf * 2048;                 \
            Ah[rf] = *reinterpret_cast<const half8*>(ab);                     \
            Am[rf] = *reinterpret_cast<const half8*>(ab + 64);                \
        }                                                                     \
        _Pragma("unroll") for (int rf = 0; rf < 2; rf++)                      \
            _Pragma("unroll") for (int cf = 0; cf < 2; cf++) {                \
                acc[rf][cf] = __builtin_amdgcn_mfma_f32_16x16x32_f16(         \
                    Am[rf], BHC[cf], acc[rf][cf], 0, 0, 0);                   \
                acc[rf][cf] = __builtin_amdgcn_mfma_f32_16x16x32_f16(         \
                    Ah[rf], BMC[cf], acc[rf][cf], 0, 0, 0);                   \
                acc[rf][cf] = __builtin_amdgcn_mfma_f32_16x16x32_f16(         \
                    Ah[rf], BHC[cf], acc[rf][cf], 0, 0, 0);                   \
            }                                                                 \
        CONV_WRITE(AVC, (cur) ^ 1);                                          \
        BAR();                                                                \
    }

    f32x4 avA, avB;
    half8 BhA[2], BmA[2], BhB[2], BmB[2];

    // ---- prologue: A(0) -> buf0; prefetch A(1), B(0) ----
    {
        const f32x4 av0 = *reinterpret_cast<const f32x4*>(xA);
        avA = *reinterpret_cast<const f32x4*>(xA + BK);   // A(1)
        LOAD_B(BhA, BmA, 0);                              // B(0)
        CONV_WRITE(av0, 0);
        BAR();
    }

    // ---- main loop: 64 steps, 2 per iteration (static buffer indices) ----
    for (int t = 0; t < NT; t += 2) {
        STEP(0, avA, avB, BhA, BmA, BhB, BmB, t);
        STEP(1, avB, avA, BhB, BmB, BhA, BmA, t + 1);
    }

#undef STEP
#undef BAR
#undef LOAD_B
#undef CONV_WRITE

    // ---- merge the two K-pipes into lg, scaled by 1/64 ----
    if (kp == 1) {
#pragma unroll
        for (int rf = 0; rf < 2; rf++)
#pragma unroll
            for (int cf = 0; cf < 2; cf++)
#pragma unroll
                for (int r = 0; r < 4; r++)
                    lg[rf * 16 + lq * 4 + r][wl * 32 + cf * 16 + lr] =
                        acc[rf][cf][r] * 0.015625f;
    }
    __syncthreads();
    if (kp == 0) {
#pragma unroll
        for (int rf = 0; rf < 2; rf++)
#pragma unroll
            for (int cf = 0; cf < 2; cf++)
#pragma unroll
                for (int r = 0; r < 4; r++)
                    lg[rf * 16 + lq * 4 + r][wl * 32 + cf * 16 + lr] +=
                        acc[rf][cf][r] * 0.015625f;
    }
    __syncthreads();

    // ---- gate epilogue ----
    if (tid < BM) {
        const int r = tid;
        const int t = row0 + r;
        float m1 = -1e30f, m2 = -1e30f;
        int   i1 = 0, i2 = 0;
        for (int e = 0; e < E_EXP; e++) {
            const float v = lg[r][e];
            if (v > m1)      { m2 = m1; i2 = i1; m1 = v; i1 = e; }
            else if (v > m2) { m2 = v; i2 = e; }
        }
        float s = 0.0f;
        for (int e = 0; e < E_EXP; e++) s += __expf(lg[r][e] - m1);
        const float inv = 1.0f / s;

        out[3 + 0 * T_TOK + t] = (float)i1;
        out[3 + 1 * T_TOK + t] = (float)i2;
        out[3 + 4 * T_TOK + t] = inv;
        out[3 + 5 * T_TOK + t] = __expf(m2 - m1) * inv;

        for (int e = 0; e < E_EXP; e++)
            lg[r][e] = __expf(lg[r][e] - m1) * inv;
    }
    __syncthreads();

    if (tid < E_EXP) {
        float s = 0.0f;
        for (int r = 0; r < BM; r++) s += lg[r][tid];
        atomicAdd(&me[tid], s);
    }
}

// ---------------------------------------------------------------------------
// Kernel B: per-expert rank. 256 blocks: e<128 scan idx1 (+ce); e>=128 do a
// ballot-count prepass over idx1 (for count1) then scan idx2.
// ---------------------------------------------------------------------------
__global__ __launch_bounds__(256) void rank_kernel(
    float* __restrict__ out, float* __restrict__ ce)
{
    const int  e      = blockIdx.x & 127;
    const bool second = blockIdx.x >= 128;
    const int  tid    = threadIdx.x;
    const int  lane   = tid & 63;
    const int  w      = tid >> 6;

    __shared__ int wtot[4];

    const float* idx1 = out + 3;
    const float* idxA = out + 3 + (second ? T_TOK : 0);
    float* loc = out + 3 + (second ? 3 * T_TOK : 2 * T_TOK);

    const unsigned long long below = (1ull << lane) - 1ull;
    int base = 0;

    if (second) {
        // count1 prepass: wave-local popcounts, one block reduce at the end
        int c = 0;
        for (int t0 = 0; t0 < T_TOK; t0 += 256)
            c += __popcll(__ballot((int)idx1[t0 + tid] == e));
        if (lane == 0) wtot[w] = c;
        __syncthreads();
        base = wtot[0] + wtot[1] + wtot[2] + wtot[3];
        __syncthreads();
    }

    for (int t0 = 0; t0 < T_TOK; t0 += 256) {
        const int t = t0 + tid;
        const int f = ((int)idxA[t] == e);
        const unsigned long long m = __ballot(f);
        const int pre = __popcll(m & below);
        const int tot = __popcll(m);
        if (lane == 0) wtot[w] = tot;
        __syncthreads();
        int off = 0;
        for (int i = 0; i < w; i++) off += wtot[i];
        const int all = wtot[0] + wtot[1] + wtot[2] + wtot[3];
        if (f) {
            const int rank = base + off + pre;
            loc[t] = (rank < CAP) ? (float)rank : 0.0f;
        }
        base += all;
        __syncthreads();
    }

    if (!second && tid == 0)
        ce[e] = (float)((base < CAP) ? base : CAP);
}

// ---------------------------------------------------------------------------
// Kernel C: l_aux = sum(me*ce) * E/(T*T); plus capacity and E constants.
// ---------------------------------------------------------------------------
__global__ __launch_bounds__(128) void finalize_kernel(
    const float* __restrict__ me, const float* __restrict__ ce,
    float* __restrict__ out)
{
    __shared__ float red[2];
    const int tid = threadIdx.x;
    float p = me[tid] * ce[tid];
#pragma unroll
    for (int o = 32; o > 0; o >>= 1) p += __shfl_down(p, o);
    if ((tid & 63) == 0) red[tid >> 6] = p;
    __syncthreads();
    if (tid == 0) {
        const float tot = red[0] + red[1];
        out[0] = tot * ((float)E_EXP / ((float)T_TOK * (float)T_TOK));
        out[1] = (float)CAP;
        out[2] = (float)E_EXP;
    }
}

extern "C" void kernel_launch(void* const* d_in, const int* in_sizes, int n_in,
                              void* d_out, int out_size, void* d_ws, size_t ws_size,
                              hipStream_t stream)
{
    const float* x  = (const float*)d_in[0];
    const float* wg = (const float*)d_in[1];
    float* out = (float*)d_out;

    float* me = (float*)d_ws;                        // 128 floats
    float* ce = me + 128;                            // 128 floats
    _Float16* wt = (_Float16*)((char*)d_ws + 1024);  // 2 MB K-tiled planes

    hipMemsetAsync(me, 0, 128 * sizeof(float), stream);
    prep_wt<<<256, 256, 0, stream>>>(wg, wt);
    gemm_gate<<<T_TOK / BM, 512, 0, stream>>>(x, wt, out, me);
    rank_kernel<<<2 * E_EXP, 256, 0, stream>>>(out, ce);
    finalize_kernel<<<1, 128, 0, stream>>>(me, ce, out);
}

// Round 7
// 118.375 us; speedup vs baseline: 3.0658x; 1.2147x over previous
//
#include <hip/hip_runtime.h>

typedef _Float16 half8 __attribute__((ext_vector_type(8)));
typedef _Float16 half4 __attribute__((ext_vector_type(4)));
typedef float    f32x4 __attribute__((ext_vector_type(4)));

#define T_TOK 16384
#define D_DIM 4096
#define E_EXP 128
#define CAP   256
#define BM    32
#define NT    32   // macro K-steps per pipe, BK=64 each (K per pipe = 2048)

// A LDS: [pipe][buf][row 0..31][256 B]. Per row: [ks=0 128B][ks=1 128B].
// Within each 128B half: 8 chunks of 16B; h data at chunk (g ^ (row&7)),
// m data at chunk ((g|4) ^ (row&7)), g = k-group 0..3. This is conflict-free
// for the 8-lane HW phases of both ds_write_b64 staging and ds_read_b128
// fragment reads (each phase covers 8 distinct bank-quads).
#define A_BUF_SZ  8192
#define A_PIPE_SZ 16384

// ---------------------------------------------------------------------------
// Kernel 0: wg (fp32) -> K-step-tiled split-fp16 planes, scaled by 64.
// Step s (BK=32) block: h plane 8192 B | m plane 8192 B; expert e at e*64 B.
// ---------------------------------------------------------------------------
__global__ __launch_bounds__(256) void prep_wt(
    const float* __restrict__ wg, _Float16* __restrict__ wt)
{
    const int t = blockIdx.x * 256 + threadIdx.x;  // 65536 threads
    const int c = t & 3;
    const int e = (t >> 2) & 127;
    const int s = t >> 9;

    const float* src = wg + (size_t)e * D_DIM + s * 32 + c * 8;
    const f32x4 v0 = *reinterpret_cast<const f32x4*>(src);
    const f32x4 v1 = *reinterpret_cast<const f32x4*>(src + 4);

    half8 h, m;
#pragma unroll
    for (int j = 0; j < 4; j++) {
        float sv = v0[j] * 64.0f;
        _Float16 hh = (_Float16)sv;
        h[j] = hh; m[j] = (_Float16)(sv - (float)hh);
        sv = v1[j] * 64.0f;
        hh = (_Float16)sv;
        h[4 + j] = hh; m[4 + j] = (_Float16)(sv - (float)hh);
    }
    _Float16* dst = wt + (size_t)s * 8192 + e * 32 + c * 8;
    *reinterpret_cast<half8*>(dst)        = h;
    *reinterpret_cast<half8*>(dst + 4096) = m;
}

// ---------------------------------------------------------------------------
// Kernel A: dual-K-pipe MFMA GEMM + fused gate epilogue + idx1 histogram.
// 512 thr = 8 waves; waves 0-3 = K-half 0, waves 4-7 = K-half 1; BK=64/step.
// A: x -> regs (1 step ahead) -> fp16 h/m split -> XOR-swizzled LDS dbuf.
// B: K-tiled wt planes direct to registers (contiguous 1KB wave-bursts, L2).
// Barrier = s_waitcnt lgkmcnt(0) + s_barrier (no vmem drain).
// ---------------------------------------------------------------------------
__global__ __launch_bounds__(512, 4) void gemm_gate(
    const float* __restrict__ x, const _Float16* __restrict__ wt,
    float* __restrict__ out, float* __restrict__ me, int* __restrict__ cnt1)
{
    __shared__ char smem[2 * A_PIPE_SZ];   // 32 KB A tiles
    __shared__ float lg[BM][E_EXP + 1];    // 16.5 KB logits

    const int tid  = threadIdx.x;
    const int row0 = blockIdx.x * BM;
    const int lane = tid & 63;
    const int w    = tid >> 6;
    const int kp   = w >> 2;     // K-pipe 0/1
    const int wl   = w & 3;      // expert group: experts wl*32 .. +32
    const int lr   = lane & 15;
    const int lq   = lane >> 4;

    // ---- A staging role: threads 0-255 stage pipe 0, 256-511 pipe 1 ----
    const int sp   = tid >> 8;
    const int srow = (tid >> 3) & 31;
    const int sg   = tid & 7;
    const float* xA = x + (size_t)(row0 + srow) * D_DIM + sp * 2048 + sg * 4;
    const int awr_h = sp * A_PIPE_SZ + srow * 256 +
                      (((sg >> 1)    ) ^ (srow & 7)) * 16 + (sg & 1) * 8;
    const int awr_m = sp * A_PIPE_SZ + srow * 256 +
                      (((sg >> 1) | 4) ^ (srow & 7)) * 16 + (sg & 1) * 8;
    // + buf*A_BUF_SZ + ks*128

    // ---- A fragment read offsets (pipe kp) ----
    const int ah_ch = ((lq    ) ^ (lr & 7)) * 16;
    const int am_ch = ((lq | 4) ^ (lr & 7)) * 16;
    const char* const ard = smem + kp * A_PIPE_SZ;
    // + cur*A_BUF_SZ + (rf*16+lr)*256 + ks*128 + {ah_ch, am_ch}

    // ---- B fragment base: sub-step s = kp*64 + 2t + ks ----
    const _Float16* const wtB =
        wt + (size_t)(kp * 64) * 8192 + (wl * 32 + lr) * 32 + lq * 8;

    f32x4 acc[2][2];
#pragma unroll
    for (int i = 0; i < 2; i++)
#pragma unroll
        for (int j = 0; j < 2; j++) acc[i][j] = (f32x4)0.0f;

#define CONV_WRITE(av0, av1, buf)                                             \
    {                                                                         \
        half4 h0, m0, h1, m1;                                                 \
        _Pragma("unroll") for (int j = 0; j < 4; j++) {                       \
            _Float16 hh = (_Float16)av0[j];                                   \
            h0[j] = hh; m0[j] = (_Float16)(av0[j] - (float)hh);               \
            hh = (_Float16)av1[j];                                            \
            h1[j] = hh; m1[j] = (_Float16)(av1[j] - (float)hh);               \
        }                                                                     \
        char* const wb = smem + (buf) * A_BUF_SZ;                             \
        *reinterpret_cast<half4*>(wb + awr_h)       = h0;                     \
        *reinterpret_cast<half4*>(wb + awr_m)       = m0;                     \
        *reinterpret_cast<half4*>(wb + awr_h + 128) = h1;                     \
        *reinterpret_cast<half4*>(wb + awr_m + 128) = m1;                     \
    }

#define BAR()                                                                 \
    asm volatile("s_waitcnt lgkmcnt(0)" ::: "memory");                        \
    __builtin_amdgcn_sched_barrier(0);                                        \
    __builtin_amdgcn_s_barrier();                                             \
    __builtin_amdgcn_sched_barrier(0);

#define SUBSTEP(cur, ks, Bh, Bm)                                              \
    {                                                                         \
        half8 Ah[2], Am[2];                                                   \
        _Pragma("unroll") for (int rf = 0; rf < 2; rf++) {                    \
            const char* ab = ard + (cur) * A_BUF_SZ +                         \
                             (rf * 16 + lr) * 256 + (ks) * 128;               \
            Ah[rf] = *reinterpret_cast<const half8*>(ab + ah_ch);             \
            Am[rf] = *reinterpret_cast<const half8*>(ab + am_ch);             \
        }                                                                     \
        _Pragma("unroll") for (int rf = 0; rf < 2; rf++)                      \
            _Pragma("unroll") for (int cf = 0; cf < 2; cf++) {                \
                acc[rf][cf] = __builtin_amdgcn_mfma_f32_16x16x32_f16(         \
                    Am[rf], Bh[cf], acc[rf][cf], 0, 0, 0);                    \
                acc[rf][cf] = __builtin_amdgcn_mfma_f32_16x16x32_f16(         \
                    Ah[rf], Bm[cf], acc[rf][cf], 0, 0, 0);                    \
                acc[rf][cf] = __builtin_amdgcn_mfma_f32_16x16x32_f16(         \
                    Ah[rf], Bh[cf], acc[rf][cf], 0, 0, 0);                    \
            }                                                                 \
    }

#define STEP(cur, A0C, A1C, A0N, A1N, t)                                      \
    {                                                                         \
        const int kn = (((t) + 2) & (NT - 1)) * 64;                           \
        A0N = *reinterpret_cast<const f32x4*>(xA + kn);                       \
        A1N = *reinterpret_cast<const f32x4*>(xA + kn + 32);                  \
        const _Float16* bp0 = wtB + (size_t)(2 * (t)) * 8192;                 \
        half8 Bh0[2], Bm0[2], Bh1[2], Bm1[2];                                 \
        _Pragma("unroll") for (int cf = 0; cf < 2; cf++) {                    \
            Bh0[cf] = *reinterpret_cast<const half8*>(bp0 + cf * 512);        \
            Bm0[cf] = *reinterpret_cast<const half8*>(bp0 + 4096 + cf * 512); \
            Bh1[cf] = *reinterpret_cast<const half8*>(bp0 + 8192 + cf * 512); \
            Bm1[cf] = *reinterpret_cast<const half8*>(bp0 + 12288 + cf * 512);\
        }                                                                     \
        SUBSTEP(cur, 0, Bh0, Bm0);                                            \
        SUBSTEP(cur, 1, Bh1, Bm1);                                            \
        CONV_WRITE(A0C, A1C, (cur) ^ 1);                                      \
        BAR();                                                                \
    }

    f32x4 avA0, avA1, avB0, avB1;

    // ---- prologue: A(0) -> buf0; prefetch A(1) regs ----
    {
        const f32x4 a00 = *reinterpret_cast<const f32x4*>(xA);
        const f32x4 a01 = *reinterpret_cast<const f32x4*>(xA + 32);
        avA0 = *reinterpret_cast<const f32x4*>(xA + 64);
        avA1 = *reinterpret_cast<const f32x4*>(xA + 96);
        CONV_WRITE(a00, a01, 0);
        BAR();
    }

    // ---- main loop: 32 macro-steps, 2 per iteration (static indices) ----
    for (int t = 0; t < NT; t += 2) {
        STEP(0, avA0, avA1, avB0, avB1, t);
        STEP(1, avB0, avB1, avA0, avA1, t + 1);
    }

#undef STEP
#undef SUBSTEP
#undef BAR
#undef CONV_WRITE

    // ---- merge the two K-pipes into lg, scaled by 1/64 ----
    if (kp == 1) {
#pragma unroll
        for (int rf = 0; rf < 2; rf++)
#pragma unroll
            for (int cf = 0; cf < 2; cf++)
#pragma unroll
                for (int r = 0; r < 4; r++)
                    lg[rf * 16 + lq * 4 + r][wl * 32 + cf * 16 + lr] =
                        acc[rf][cf][r] * 0.015625f;
    }
    __syncthreads();
    if (kp == 0) {
#pragma unroll
        for (int rf = 0; rf < 2; rf++)
#pragma unroll
            for (int cf = 0; cf < 2; cf++)
#pragma unroll
                for (int r = 0; r < 4; r++)
                    lg[rf * 16 + lq * 4 + r][wl * 32 + cf * 16 + lr] +=
                        acc[rf][cf][r] * 0.015625f;
    }
    __syncthreads();

    // ---- gate epilogue ----
    if (tid < BM) {
        const int r = tid;
        const int t = row0 + r;
        float m1 = -1e30f, m2 = -1e30f;
        int   i1 = 0, i2 = 0;
        for (int e = 0; e < E_EXP; e++) {
            const float v = lg[r][e];
            if (v > m1)      { m2 = m1; i2 = i1; m1 = v; i1 = e; }
            else if (v > m2) { m2 = v; i2 = e; }
        }
        float s = 0.0f;
        for (int e = 0; e < E_EXP; e++) s += __expf(lg[r][e] - m1);
        const float inv = 1.0f / s;

        out[3 + 0 * T_TOK + t] = (float)i1;
        out[3 + 1 * T_TOK + t] = (float)i2;
        out[3 + 4 * T_TOK + t] = inv;
        out[3 + 5 * T_TOK + t] = __expf(m2 - m1) * inv;
        atomicAdd(&cnt1[i1], 1);

        for (int e = 0; e < E_EXP; e++)
            lg[r][e] = __expf(lg[r][e] - m1) * inv;
    }
    __syncthreads();

    if (tid < E_EXP) {
        float s = 0.0f;
        for (int r = 0; r < BM; r++) s += lg[r][tid];
        atomicAdd(&me[tid], s);
    }
}

// ---------------------------------------------------------------------------
// Kernel B: per-expert rank. 256 blocks x 1024 thr: blocks 0-127 scan idx1;
// blocks 128-255 scan idx2 starting at base = cnt1[e] (from gemm histogram).
// ---------------------------------------------------------------------------
__global__ __launch_bounds__(1024) void rank_kernel(
    float* __restrict__ out, const int* __restrict__ cnt1)
{
    const int  e      = blockIdx.x & 127;
    const bool second = blockIdx.x >= 128;
    const int  tid    = threadIdx.x;
    const int  lane   = tid & 63;
    const int  w      = tid >> 6;   // 0..15

    __shared__ int wtot[16];

    const float* idxA = out + 3 + (second ? T_TOK : 0);
    float* loc = out + 3 + (second ? 3 * T_TOK : 2 * T_TOK);

    const unsigned long long below = (1ull << lane) - 1ull;
    int base = second ? cnt1[e] : 0;

    for (int t0 = 0; t0 < T_TOK; t0 += 1024) {
        const int t = t0 + tid;
        const int f = ((int)idxA[t] == e);
        const unsigned long long m = __ballot(f);
        const int pre = __popcll(m & below);
        const int tot = __popcll(m);
        if (lane == 0) wtot[w] = tot;
        __syncthreads();
        int off = 0, all = 0;
#pragma unroll
        for (int i = 0; i < 16; i++) {
            const int v = wtot[i];
            if (i < w) off += v;
            all += v;
        }
        if (f) {
            const int rank = base + off + pre;
            loc[t] = (rank < CAP) ? (float)rank : 0.0f;
        }
        base += all;
        __syncthreads();
    }
}

// ---------------------------------------------------------------------------
// Kernel C: l_aux = sum(me * min(cnt1,CAP)) * E/(T*T); plus constants.
// ---------------------------------------------------------------------------
__global__ __launch_bounds__(128) void finalize_kernel(
    const float* __restrict__ me, const int* __restrict__ cnt1,
    float* __restrict__ out)
{
    __shared__ float red[2];
    const int tid = threadIdx.x;
    const int c = cnt1[tid];
    float p = me[tid] * (float)((c < CAP) ? c : CAP);
#pragma unroll
    for (int o = 32; o > 0; o >>= 1) p += __shfl_down(p, o);
    if ((tid & 63) == 0) red[tid >> 6] = p;
    __syncthreads();
    if (tid == 0) {
        const float tot = red[0] + red[1];
        out[0] = tot * ((float)E_EXP / ((float)T_TOK * (float)T_TOK));
        out[1] = (float)CAP;
        out[2] = (float)E_EXP;
    }
}

extern "C" void kernel_launch(void* const* d_in, const int* in_sizes, int n_in,
                              void* d_out, int out_size, void* d_ws, size_t ws_size,
                              hipStream_t stream)
{
    const float* x  = (const float*)d_in[0];
    const float* wg = (const float*)d_in[1];
    float* out = (float*)d_out;

    float* me   = (float*)d_ws;                      // 128 floats
    int*   cnt1 = (int*)((char*)d_ws + 512);         // 128 ints
    _Float16* wt = (_Float16*)((char*)d_ws + 1024);  // 2 MB K-tiled planes

    hipMemsetAsync(d_ws, 0, 1024, stream);
    prep_wt<<<256, 256, 0, stream>>>(wg, wt);
    gemm_gate<<<T_TOK / BM, 512, 0, stream>>>(x, wt, out, me, cnt1);
    rank_kernel<<<2 * E_EXP, 1024, 0, stream>>>(out, cnt1);
    finalize_kernel<<<1, 128, 0, stream>>>(me, cnt1, out);
}